// Round 13
// baseline (306.545 us; speedup 1.0000x reference)
//
#include <hip/hip_runtime.h>
#include <hip/hip_bf16.h>
#include <cstdint>

#define CAP 48
#define SLICES 8
#define CHUNK_EDGES 2048

__device__ __forceinline__ float lrelu(float v) { return fmaxf(v, 0.2f * v); }

typedef float f32x2 __attribute__((ext_vector_type(2)));
// encode 4 floats -> 4 packed fp8 bytes
__device__ __forceinline__ int f2q4(float a, float b, float c, float d) {
    int p = __builtin_amdgcn_cvt_pk_fp8_f32(a, b, 0, false);
    p = __builtin_amdgcn_cvt_pk_fp8_f32(c, d, p, true);
    return p;
}
// exact bf16<->f32 (RNE), finite values only
__device__ __forceinline__ float b2f(unsigned short u) { return __uint_as_float(((unsigned)u) << 16); }
__device__ __forceinline__ unsigned short f2b(float f) {
    unsigned u = __float_as_uint(f);
    return (unsigned short)((u + 0x7FFFu + ((u >> 16) & 1u)) >> 16);
}

// ---------------- fused: CSR bucket build (XCD-sliced) + GEMM1/alpha1 ----------------
// FUSED single dispatch is essential (R9: 3-way split ran 225us vs 120us).
__global__ __launch_bounds__(256, 4) void k_bg(const int* __restrict__ ei, int E, int N,
                                               int* __restrict__ cnt, int* __restrict__ bucket,
                                               const float* __restrict__ x,
                                               const float* __restrict__ W,
                                               const float* __restrict__ asrc,
                                               const float* __restrict__ adst,
                                               unsigned char* __restrict__ h1feat,
                                               unsigned short* __restrict__ als16,
                                               float* __restrict__ ald,
                                               int buildBlocks) {
    __shared__ unsigned short xs[64 * 132];
    if ((int)blockIdx.x < buildBlocks) {
        const int s = blockIdx.x & (SLICES - 1);
        const int chunk = blockIdx.x >> 3;
        const int sliceN = (N + SLICES - 1) / SLICES;
        const int lo = s * sliceN;
        const int hi = min(N, lo + sliceN);
        const int base = chunk * CHUNK_EDGES;
        if (base + CHUNK_EDGES <= E) {
            const int e0 = base + (int)threadIdx.x * 4;
            const int e1 = e0 + 1024;
            int4 d0 = *(const int4*)(ei + E + e0);
            int4 s0 = *(const int4*)(ei + e0);
            int4 d1 = *(const int4*)(ei + E + e1);
            int4 s1 = *(const int4*)(ei + e1);
            int a0 = -1, a1 = -1, a2 = -1, a3 = -1, a4 = -1, a5 = -1, a6 = -1, a7 = -1;
            // atomic phase: 8 independent round-trips in flight
            if (d0.x >= lo && d0.x < hi) a0 = atomicAdd(&cnt[d0.x], 1);
            if (d0.y >= lo && d0.y < hi) a1 = atomicAdd(&cnt[d0.y], 1);
            if (d0.z >= lo && d0.z < hi) a2 = atomicAdd(&cnt[d0.z], 1);
            if (d0.w >= lo && d0.w < hi) a3 = atomicAdd(&cnt[d0.w], 1);
            if (d1.x >= lo && d1.x < hi) a4 = atomicAdd(&cnt[d1.x], 1);
            if (d1.y >= lo && d1.y < hi) a5 = atomicAdd(&cnt[d1.y], 1);
            if (d1.z >= lo && d1.z < hi) a6 = atomicAdd(&cnt[d1.z], 1);
            if (d1.w >= lo && d1.w < hi) a7 = atomicAdd(&cnt[d1.w], 1);
            // store phase
            if (a0 >= 0 && a0 < CAP) bucket[(size_t)d0.x * CAP + a0] = s0.x;
            if (a1 >= 0 && a1 < CAP) bucket[(size_t)d0.y * CAP + a1] = s0.y;
            if (a2 >= 0 && a2 < CAP) bucket[(size_t)d0.z * CAP + a2] = s0.z;
            if (a3 >= 0 && a3 < CAP) bucket[(size_t)d0.w * CAP + a3] = s0.w;
            if (a4 >= 0 && a4 < CAP) bucket[(size_t)d1.x * CAP + a4] = s1.x;
            if (a5 >= 0 && a5 < CAP) bucket[(size_t)d1.y * CAP + a5] = s1.y;
            if (a6 >= 0 && a6 < CAP) bucket[(size_t)d1.z * CAP + a6] = s1.z;
            if (a7 >= 0 && a7 < CAP) bucket[(size_t)d1.w * CAP + a7] = s1.w;
        } else {
            const int end = E;
            for (int e = base + (int)threadIdx.x; e < end; e += 256) {
                int d = ei[E + e];
                if (d >= lo && d < hi) {
                    int a = atomicAdd(&cnt[d], 1);
                    if (a < CAP) bucket[(size_t)d * CAP + a] = ei[e];
                }
            }
        }
        return;
    }
    // ---- gemm1 path ----
    const int t = threadIdx.x;
    const int rowBase = ((int)blockIdx.x - buildBlocks) * 64;
#pragma unroll
    for (int i = 0; i < 8; ++i) {
        int g = i * 256 + t;
        int r = g >> 5, c4 = (g & 31) << 2;
        float4 v = make_float4(0.f, 0.f, 0.f, 0.f);
        int row = rowBase + r;
        if (row < N) v = *(const float4*)(x + (size_t)row * 128 + c4);
        ushort4 u;
        u.x = f2b(v.x); u.y = f2b(v.y); u.z = f2b(v.z); u.w = f2b(v.w);
        *(ushort4*)(&xs[r * 132 + c4]) = u;
    }
    __syncthreads();
    const int tx = t & 15;   // cols 4tx..4tx+3 (head tx>>1)
    const int ty = t >> 4;   // rows 4ty..4ty+3
    float acc[4][4] = {};
#pragma unroll 2
    for (int kc = 0; kc < 32; ++kc) {
        float a_[4][4];
#pragma unroll
        for (int i = 0; i < 4; ++i) {
            ushort4 u = *(const ushort4*)(&xs[(4 * ty + i) * 132 + kc * 4]);
            a_[i][0] = b2f(u.x); a_[i][1] = b2f(u.y); a_[i][2] = b2f(u.z); a_[i][3] = b2f(u.w);
        }
        float4 w[4];
#pragma unroll
        for (int kk = 0; kk < 4; ++kk) w[kk] = *(const float4*)(W + (size_t)(kc * 4 + kk) * 64 + tx * 4);
#pragma unroll
        for (int i = 0; i < 4; ++i) {
#pragma unroll
            for (int j = 0; j < 4; ++j) {
                acc[i][j] += a_[i][0] * ((const float*)&w[0])[j]
                           + a_[i][1] * ((const float*)&w[1])[j]
                           + a_[i][2] * ((const float*)&w[2])[j]
                           + a_[i][3] * ((const float*)&w[3])[j];
            }
        }
    }
    const int h = tx >> 1;
    float4 av = *(const float4*)(asrc + tx * 4);
    float4 dv = *(const float4*)(adst + tx * 4);
    __syncthreads();                          // xs bf16 reads done; reuse as staging
    unsigned char* qs = (unsigned char*)xs;   // feat: 64 rows x 64 B = 4096 B
    unsigned short* as_st = xs + 2048;        // als : 64 rows x 8 ushort = 1024 B
#pragma unroll
    for (int i = 0; i < 4; ++i) {
        int row = rowBase + 4 * ty + i;
        float ps = acc[i][0] * av.x + acc[i][1] * av.y + acc[i][2] * av.z + acc[i][3] * av.w;
        float pd = acc[i][0] * dv.x + acc[i][1] * dv.y + acc[i][2] * dv.z + acc[i][3] * dv.w;
        ps += __shfl_xor(ps, 1);
        pd += __shfl_xor(pd, 1);
        *(int*)(qs + (4 * ty + i) * 64 + h * 8 + (tx & 1) * 4) =
            f2q4(acc[i][0], acc[i][1], acc[i][2], acc[i][3]);
        if ((tx & 1) == 0) {
            as_st[(4 * ty + i) * 8 + h] = f2b(ps);
            if (row < N) ald[(size_t)row * 8 + h] = pd;
        }
    }
    __syncthreads();
    // coalesced copy-out: feat 1024 uints, als 256 uints
    {
        unsigned int* qsu = (unsigned int*)xs;
        for (int g = t; g < 1024; g += 256) {
            int row = g >> 4;                 // 16 uints per 64-B row
            if (rowBase + row < N)
                *(unsigned int*)(h1feat + (size_t)rowBase * 64 + (size_t)g * 4) = qsu[g];
        }
        unsigned int* asu = (unsigned int*)as_st;
        if (t < 256) {
            int g = t;
            if (g < 256) {
                int row = g >> 2;             // 4 uints per 16-B row
                if (rowBase + row < N)
                    *(unsigned int*)((unsigned char*)als16 + (size_t)rowBase * 16 + (size_t)g * 4) = asu[g];
            }
        }
    }
}

// ---------------- R13: cache-warm pass for the layer-1 gather tables ----------------
// R9 counters: k_ag FETCH_SIZE = 143.6 MB == its ENTIRE logical gather volume
// -- after k_bg's ~250 MB scatter storm, bucket/h1feat are cold everywhere.
// k_agg2 is 3x faster running the SAME code because its predecessor (k_ag)
// left bucket L2-hot (same block->node mapping) and h2q L3-hot. This kernel
// reproduces that state for k_ag: block b streams the bucket/h1feat/als16
// lines that k_ag block b (and its random gathers) will hit. ~27 MB coalesced
// ~= 6-10 us. Checksum store prevents DCE.
__global__ __launch_bounds__(256) void k_warm(const int* __restrict__ bucket,
                                              const unsigned char* __restrict__ h1feat,
                                              const unsigned short* __restrict__ als16,
                                              int* __restrict__ scratch, int N) {
    const int t = threadIdx.x;
    const int b = blockIdx.x;
    const int nodeBase = b * 32;
    if (nodeBase >= N) return;
    const int nn = min(32, N - nodeBase);
    int acc = 0;
    const int* bp = bucket + (size_t)nodeBase * CAP;
    const int lim0 = nn * CAP;                 // 1536 ints
    for (int i = t; i < lim0; i += 256) acc ^= bp[i];
    const int* fp = (const int*)(h1feat + (size_t)nodeBase * 64);
    const int lim1 = nn * 16;                  // 512 ints
    for (int i = t; i < lim1; i += 256) acc ^= fp[i];
    const int* ap = (const int*)((const unsigned char*)als16 + (size_t)nodeBase * 16);
    const int lim2 = nn * 4;                   // 128 ints
    for (int i = t; i < lim2; i += 256) acc ^= ap[i];
    if (t == 0) scratch[b] = acc;
}

// ---------------- FUSED layer-1 aggregation + GEMM2 + alpha2 (R10/R12 structure) ----------------
__global__ __launch_bounds__(256) void k_ag(const int* __restrict__ cnt, const int* __restrict__ bucket,
                                            const unsigned char* __restrict__ h1feat,
                                            const unsigned short* __restrict__ als16,
                                            const float* __restrict__ aldin,
                                            const float* __restrict__ b1,
                                            const float* __restrict__ W,
                                            const float* __restrict__ asrc,
                                            const float* __restrict__ adst,
                                            unsigned char* __restrict__ h2q,
                                            float* __restrict__ ald, int N) {
    __shared__ unsigned short xs[32 * 68];   // bf16 agg1 output; reused as fp8 staging
    __shared__ unsigned short wt[80 * 68];   // bf16 W2^T
    const int t = threadIdx.x;
    const int rowBase = blockIdx.x * 32;
    // stage W2^T in bf16 (phase-B only; issued first to overlap phase A)
#pragma unroll
    for (int i = 0; i < 20; ++i) {
        int g = i * 256 + t;
        int k = g / 80, c = g % 80;
        wt[c * 68 + k] = f2b(W[g]);
    }
    // ---- phase A: 1 lane per (node, head); 8 lanes/node ----
    {
        const int nl = t >> 3;               // local node 0..31
        const int h = t & 7;
        const int n = rowBase + nl;
        if (n < N) {
            const float aldh = aldin[(size_t)n * 8 + h];
            float acc[8] = {};
            float den = 0.f;
            auto body = [&](int m0, int m1, float a_s, float val) {
                float wl = __expf(lrelu(a_s + aldh)) * val;
                den += wl;
                f32x2 v;
                v = __builtin_amdgcn_cvt_pk_f32_fp8(m0, false); acc[0] += wl * v.x; acc[1] += wl * v.y;
                v = __builtin_amdgcn_cvt_pk_f32_fp8(m0, true);  acc[2] += wl * v.x; acc[3] += wl * v.y;
                v = __builtin_amdgcn_cvt_pk_f32_fp8(m1, false); acc[4] += wl * v.x; acc[5] += wl * v.y;
                v = __builtin_amdgcn_cvt_pk_f32_fp8(m1, true);  acc[6] += wl * v.x; acc[7] += wl * v.y;
            };
            {   // self loop
                const unsigned char* r = h1feat + (size_t)n * 64 + h * 8;
                body(*(const int*)r, *(const int*)(r + 4), b2f(als16[(size_t)n * 8 + h]), 1.f);
            }
            const int k = min(cnt[n], CAP);
            const int* bp = bucket + (size_t)n * CAP;
            if (k > 0) {
                const int kg4 = ((k - 1) >> 2) << 2;       // last valid 4-group start
                int4 lo = *(const int4*)(bp);
                int4 hi = *(const int4*)(bp + min(4, kg4));
                for (int i0 = 0; i0 < k; i0 += 8) {
                    int4 cA = lo, cB = hi;
                    lo = *(const int4*)(bp + min(i0 + 8, kg4));    // always-safe prefetch
                    hi = *(const int4*)(bp + min(i0 + 12, kg4));
                    const int rem = k - i0;
                    int s[8];
                    s[0] = cA.x;
                    s[1] = (rem > 1) ? cA.y : cA.x;
                    s[2] = (rem > 2) ? cA.z : cA.x;
                    s[3] = (rem > 3) ? cA.w : cA.x;
                    s[4] = (rem > 4) ? cB.x : cA.x;
                    s[5] = (rem > 5) ? cB.y : cA.x;
                    s[6] = (rem > 6) ? cB.z : cA.x;
                    s[7] = (rem > 7) ? cB.w : cA.x;
                    int m0[8], m1[8];
                    float as[8];
#pragma unroll
                    for (int j = 0; j < 8; ++j) {
                        const unsigned char* p = h1feat + (size_t)s[j] * 64 + h * 8;
                        m0[j] = *(const int*)p;
                        m1[j] = *(const int*)(p + 4);
                        as[j] = b2f(als16[(size_t)s[j] * 8 + h]);
                    }
#pragma unroll
                    for (int j = 0; j < 8; ++j) body(m0[j], m1[j], as[j], (rem > j) ? 1.f : 0.f);
                }
            }
            float inv = 1.f / den;
            float o[8];
#pragma unroll
            for (int j = 0; j < 8; ++j) {
                float v = acc[j] * inv + b1[h * 8 + j];
                o[j] = v > 0.f ? v : __expf(v) - 1.f;
            }
            unsigned short* dst = &xs[nl * 68 + h * 8];
            ushort4 u0, u1;
            u0.x = f2b(o[0]); u0.y = f2b(o[1]); u0.z = f2b(o[2]); u0.w = f2b(o[3]);
            u1.x = f2b(o[4]); u1.y = f2b(o[5]); u1.z = f2b(o[6]); u1.w = f2b(o[7]);
            *(ushort4*)(dst) = u0;
            *(ushort4*)(dst + 4) = u1;
        }
    }
    __syncthreads();
    // ---- phase B: gemm2 + alpha2 on 32-row tile ----
    const int tx = t & 15;   // cols 5tx..5tx+4 (head tx>>1)
    const int ty = t >> 4;   // rows 2ty, 2ty+1
    float acc[2][5] = {};
#pragma unroll 4
    for (int kc = 0; kc < 16; ++kc) {
        float4 a[2];
#pragma unroll
        for (int i = 0; i < 2; ++i) {
            ushort4 u = *(const ushort4*)(&xs[(2 * ty + i) * 68 + kc * 4]);
            a[i] = make_float4(b2f(u.x), b2f(u.y), b2f(u.z), b2f(u.w));
        }
        float4 w[5];
#pragma unroll
        for (int j = 0; j < 5; ++j) {
            ushort4 u = *(const ushort4*)(&wt[(5 * tx + j) * 68 + kc * 4]);
            w[j] = make_float4(b2f(u.x), b2f(u.y), b2f(u.z), b2f(u.w));
        }
#pragma unroll
        for (int i = 0; i < 2; ++i) {
#pragma unroll
            for (int j = 0; j < 5; ++j) {
                acc[i][j] += a[i].x * w[j].x + a[i].y * w[j].y + a[i].z * w[j].z + a[i].w * w[j].w;
            }
        }
    }
    const int h = tx >> 1;
    float a2[5], d2[5];
#pragma unroll
    for (int j = 0; j < 5; ++j) { a2[j] = asrc[tx * 5 + j]; d2[j] = adst[tx * 5 + j]; }
    __syncthreads();                         // xs reads done; reuse as staging
    unsigned char* qs = (unsigned char*)xs;  // 32 rows x 96 B = 3072 B
#pragma unroll
    for (int i = 0; i < 2; ++i) {
        int row = rowBase + 2 * ty + i;
        float ps = 0.f, pd = 0.f;
#pragma unroll
        for (int j = 0; j < 5; ++j) { ps += acc[i][j] * a2[j]; pd += acc[i][j] * d2[j]; }
        ps += __shfl_xor(ps, 1);
        pd += __shfl_xor(pd, 1);
        int p0 = __builtin_amdgcn_cvt_pk_fp8_f32(acc[i][0], acc[i][1], 0, false);
        int p1 = __builtin_amdgcn_cvt_pk_fp8_f32(acc[i][2], acc[i][3], 0, false);
        int p2 = __builtin_amdgcn_cvt_pk_fp8_f32(acc[i][4], acc[i][4], 0, false);
        unsigned char* q = qs + (2 * ty + i) * 96 + h * 12 + (tx & 1) * 5;
        q[0] = (unsigned char)(p0 & 0xFF);
        q[1] = (unsigned char)((p0 >> 8) & 0xFF);
        q[2] = (unsigned char)(p1 & 0xFF);
        q[3] = (unsigned char)((p1 >> 8) & 0xFF);
        q[4] = (unsigned char)(p2 & 0xFF);
        if ((tx & 1) == 0) {
            *(unsigned short*)(qs + (size_t)(2 * ty + i) * 96 + h * 12 + 10) = f2b(ps);
            if (row < N) ald[(size_t)row * 8 + h] = pd;
        }
    }
    __syncthreads();
    // coalesced copy-out: 32 rows x 96 B = 768 uints
    for (int g = t; g < 768; g += 256) {
        int row = g / 24;
        if (rowBase + row < N)
            *(unsigned int*)(h2q + (size_t)rowBase * 96 + (size_t)g * 4) = ((unsigned int*)qs)[g];
    }
}

// ---------------- layer-2 aggregation (unchanged -- the proven-fast kernel) ----------------
__global__ __launch_bounds__(256) void k_agg2(const int* __restrict__ cnt, const int* __restrict__ bucket,
                                              const unsigned char* __restrict__ h2q,
                                              const float* __restrict__ ald,
                                              const float* __restrict__ b2,
                                              float* __restrict__ out, int N) {
    const int t = threadIdx.x;
    const int n = blockIdx.x * 32 + (t >> 3);
    const int h = t & 7;
    if (n >= N) return;
    float acc[10] = {};
    float den = 0.f;
    const float aldh = ald[(size_t)n * 8 + h];
    auto body = [&](int m0, int m1, int m2, float val) {
        float a_s = b2f((unsigned short)(((unsigned)m2) >> 16));
        float wl = __expf(lrelu(a_s + aldh)) * val;
        den += wl;
        f32x2 v;
        v = __builtin_amdgcn_cvt_pk_f32_fp8(m0, false); acc[0] += wl * v.x; acc[1] += wl * v.y;
        v = __builtin_amdgcn_cvt_pk_f32_fp8(m0, true);  acc[2] += wl * v.x; acc[3] += wl * v.y;
        v = __builtin_amdgcn_cvt_pk_f32_fp8(m1, false); acc[4] += wl * v.x; acc[5] += wl * v.y;
        v = __builtin_amdgcn_cvt_pk_f32_fp8(m1, true);  acc[6] += wl * v.x; acc[7] += wl * v.y;
        v = __builtin_amdgcn_cvt_pk_f32_fp8(m2, false); acc[8] += wl * v.x; acc[9] += wl * v.y;
    };
    {   // self loop
        const unsigned char* r = h2q + (size_t)n * 96 + h * 12;
        body(*(const int*)r, *(const int*)(r + 4), *(const int*)(r + 8), 1.f);
    }
    const int k = min(cnt[n], CAP);
    const int* bp = bucket + (size_t)n * CAP;
    if (k > 0) {
        const int kg4 = ((k - 1) >> 2) << 2;
        int4 lo = *(const int4*)(bp);
        int4 hi = *(const int4*)(bp + min(4, kg4));
        for (int i0 = 0; i0 < k; i0 += 8) {
            int4 cA = lo, cB = hi;
            lo = *(const int4*)(bp + min(i0 + 8, kg4));
            hi = *(const int4*)(bp + min(i0 + 12, kg4));
            const int rem = k - i0;
            int s[8];
            s[0] = cA.x;
            s[1] = (rem > 1) ? cA.y : cA.x;
            s[2] = (rem > 2) ? cA.z : cA.x;
            s[3] = (rem > 3) ? cA.w : cA.x;
            s[4] = (rem > 4) ? cB.x : cA.x;
            s[5] = (rem > 5) ? cB.y : cA.x;
            s[6] = (rem > 6) ? cB.z : cA.x;
            s[7] = (rem > 7) ? cB.w : cA.x;
            int m0[8], m1[8], m2[8];
#pragma unroll
            for (int j = 0; j < 8; ++j) {
                const unsigned char* p = h2q + (size_t)s[j] * 96 + h * 12;
                m0[j] = *(const int*)p;
                m1[j] = *(const int*)(p + 4);
                m2[j] = *(const int*)(p + 8);
            }
#pragma unroll
            for (int j = 0; j < 8; ++j) body(m0[j], m1[j], m2[j], (rem > j) ? 1.f : 0.f);
        }
    }
    float inv = 1.f / den;
#pragma unroll
    for (int j = 0; j < 10; ++j) acc[j] *= inv;
#pragma unroll
    for (int off = 1; off < 8; off <<= 1) {
#pragma unroll
        for (int j = 0; j < 10; ++j) acc[j] += __shfl_xor(acc[j], off);
    }
    if (h == 0) {
        float m[10];
#pragma unroll
        for (int j = 0; j < 10; ++j) m[j] = acc[j] * 0.125f + b2[j];
        float mx = -1e30f;
#pragma unroll
        for (int j = 0; j < 10; ++j) mx = fmaxf(mx, m[j]);
        float ssum = 0.f;
#pragma unroll
        for (int j = 0; j < 10; ++j) ssum += __expf(m[j] - mx);
        float lg = __logf(ssum);
#pragma unroll
        for (int j = 0; j < 10; ++j) out[(size_t)n * 10 + j] = m[j] - mx - lg;
    }
}

extern "C" void kernel_launch(void* const* d_in, const int* in_sizes, int n_in,
                              void* d_out, int out_size, void* d_ws, size_t ws_size,
                              hipStream_t stream) {
    const float* x     = (const float*)d_in[0];
    const int*   ei    = (const int*)d_in[1];
    const float* W1    = (const float*)d_in[2];
    const float* asrc1 = (const float*)d_in[3];
    const float* adst1 = (const float*)d_in[4];
    const float* b1    = (const float*)d_in[5];
    const float* W2    = (const float*)d_in[6];
    const float* asrc2 = (const float*)d_in[7];
    const float* adst2 = (const float*)d_in[8];
    const float* b2    = (const float*)d_in[9];
    float* out = (float*)d_out;

    int N = in_sizes[0] / 128;
    int E = in_sizes[1] / 2;

    char* base = (char*)d_ws;
    size_t off = 0;
    auto alloc = [&](size_t bytes) {
        char* p = base + off;
        off = (off + bytes + 255) & ~(size_t)255;
        return p;
    };
    int*             cnt    = (int*)alloc((size_t)N * 4);
    int*             bucket = (int*)alloc((size_t)N * CAP * 4);
    unsigned char*   h1feat = (unsigned char*)alloc((size_t)N * 64);     // layer-1: 8 heads x 8 fp8 (one line/row)
    unsigned short*  als16  = (unsigned short*)alloc((size_t)N * 8 * 2); // layer-1 als, bf16
    unsigned char*   h2q    = (unsigned char*)alloc((size_t)N * 96);     // layer-2: 8 heads x [10 fp8 | bf16 als]
    float*           ald    = (float*)alloc((size_t)N * 8 * 4);          // layer1 then layer2
    int*             scratch= (int*)alloc((size_t)((N + 31) / 32) * 4);  // k_warm checksum sink
    (void)ws_size; (void)n_in; (void)out_size;

    (void)hipMemsetAsync(cnt, 0, (size_t)N * 4, stream);
    int chunks = (E + CHUNK_EDGES - 1) / CHUNK_EDGES;
    int buildBlocks = chunks * SLICES;
    int gemmBlocks = (N + 63) / 64;
    k_bg<<<buildBlocks + gemmBlocks, 256, 0, stream>>>(ei, E, N, cnt, bucket,
                                                       x, W1, asrc1, adst1, h1feat, als16, ald, buildBlocks);
    k_warm<<<(N + 31) / 32, 256, 0, stream>>>(bucket, h1feat, als16, scratch, N);
    k_ag<<<(N + 31) / 32, 256, 0, stream>>>(cnt, bucket, h1feat, als16, ald, b1,
                                            W2, asrc2, adst2, h2q, ald, N);
    k_agg2<<<(N + 31) / 32, 256, 0, stream>>>(cnt, bucket, h2q, ald, b2, out, N);
}

// Round 14
// 297.338 us; speedup vs baseline: 1.0310x; 1.0310x over previous
//
#include <hip/hip_runtime.h>
#include <hip/hip_bf16.h>
#include <cstdint>

#define CAP 64
#define SLICES 8
#define CHUNK_EDGES 2048

__device__ __forceinline__ float lrelu(float v) { return fmaxf(v, 0.2f * v); }

typedef float f32x2 __attribute__((ext_vector_type(2)));
// encode 4 floats -> 4 packed fp8 bytes
__device__ __forceinline__ int f2q4(float a, float b, float c, float d) {
    int p = __builtin_amdgcn_cvt_pk_fp8_f32(a, b, 0, false);
    p = __builtin_amdgcn_cvt_pk_fp8_f32(c, d, p, true);
    return p;
}
// exact bf16<->f32 (RNE), finite values only
__device__ __forceinline__ float b2f(unsigned short u) { return __uint_as_float(((unsigned)u) << 16); }
__device__ __forceinline__ unsigned short f2b(float f) {
    unsigned u = __float_as_uint(f);
    return (unsigned short)((u + 0x7FFFu + ((u >> 16) & 1u)) >> 16);
}

// ---------------- fused: CSR bucket build (XCD-sliced) + GEMM1/alpha1 ----------------
// FUSED single dispatch is essential: R9's 3-way split ran 225us vs 120us
// fused -- the one big grid keeps all XCD-sliced build blocks co-resident so
// each XCD's L2 owns its cnt/bucket slice. Do not split again.
// Build is at the random-scatter service floor (~1.4 TB/s mixed 64-B-granule
// traffic): occupancy, spills, atomic chain depth, nontemporal hints, and CAP
// shrink all measured flat (R0-R12).
// gemm1 emits h1q in the 96-B h2q-style layout (per head 12 B =
// [8 fp8 | bf16 als | 2 pad]) via LDS staging + coalesced copy-out.
__global__ __launch_bounds__(256, 4) void k_bg(const int* __restrict__ ei, int E, int N,
                                               int* __restrict__ cnt, int* __restrict__ bucket,
                                               const float* __restrict__ x,
                                               const float* __restrict__ W,
                                               const float* __restrict__ asrc,
                                               const float* __restrict__ adst,
                                               unsigned char* __restrict__ h1q,
                                               float* __restrict__ ald,
                                               int buildBlocks) {
    __shared__ unsigned short xs[64 * 132];
    if ((int)blockIdx.x < buildBlocks) {
        const int s = blockIdx.x & (SLICES - 1);
        const int chunk = blockIdx.x >> 3;
        const int sliceN = (N + SLICES - 1) / SLICES;
        const int lo = s * sliceN;
        const int hi = min(N, lo + sliceN);
        const int base = chunk * CHUNK_EDGES;
        if (base + CHUNK_EDGES <= E) {
            const int e0 = base + (int)threadIdx.x * 4;
            const int e1 = e0 + 1024;
            int4 d0 = *(const int4*)(ei + E + e0);
            int4 s0 = *(const int4*)(ei + e0);
            int4 d1 = *(const int4*)(ei + E + e1);
            int4 s1 = *(const int4*)(ei + e1);
            int a0 = -1, a1 = -1, a2 = -1, a3 = -1, a4 = -1, a5 = -1, a6 = -1, a7 = -1;
            // atomic phase: 8 independent round-trips in flight
            if (d0.x >= lo && d0.x < hi) a0 = atomicAdd(&cnt[d0.x], 1);
            if (d0.y >= lo && d0.y < hi) a1 = atomicAdd(&cnt[d0.y], 1);
            if (d0.z >= lo && d0.z < hi) a2 = atomicAdd(&cnt[d0.z], 1);
            if (d0.w >= lo && d0.w < hi) a3 = atomicAdd(&cnt[d0.w], 1);
            if (d1.x >= lo && d1.x < hi) a4 = atomicAdd(&cnt[d1.x], 1);
            if (d1.y >= lo && d1.y < hi) a5 = atomicAdd(&cnt[d1.y], 1);
            if (d1.z >= lo && d1.z < hi) a6 = atomicAdd(&cnt[d1.z], 1);
            if (d1.w >= lo && d1.w < hi) a7 = atomicAdd(&cnt[d1.w], 1);
            // store phase: each store waits only on its own atomic's return
            if (a0 >= 0 && a0 < CAP) bucket[(size_t)d0.x * CAP + a0] = s0.x;
            if (a1 >= 0 && a1 < CAP) bucket[(size_t)d0.y * CAP + a1] = s0.y;
            if (a2 >= 0 && a2 < CAP) bucket[(size_t)d0.z * CAP + a2] = s0.z;
            if (a3 >= 0 && a3 < CAP) bucket[(size_t)d0.w * CAP + a3] = s0.w;
            if (a4 >= 0 && a4 < CAP) bucket[(size_t)d1.x * CAP + a4] = s1.x;
            if (a5 >= 0 && a5 < CAP) bucket[(size_t)d1.y * CAP + a5] = s1.y;
            if (a6 >= 0 && a6 < CAP) bucket[(size_t)d1.z * CAP + a6] = s1.z;
            if (a7 >= 0 && a7 < CAP) bucket[(size_t)d1.w * CAP + a7] = s1.w;
        } else {
            const int end = E;
            for (int e = base + (int)threadIdx.x; e < end; e += 256) {
                int d = ei[E + e];
                if (d >= lo && d < hi) {
                    int a = atomicAdd(&cnt[d], 1);
                    if (a < CAP) bucket[(size_t)d * CAP + a] = ei[e];
                }
            }
        }
        return;
    }
    // ---- gemm1 path ----
    const int t = threadIdx.x;
    const int rowBase = ((int)blockIdx.x - buildBlocks) * 64;
#pragma unroll
    for (int i = 0; i < 8; ++i) {
        int g = i * 256 + t;
        int r = g >> 5, c4 = (g & 31) << 2;
        float4 v = make_float4(0.f, 0.f, 0.f, 0.f);
        int row = rowBase + r;
        if (row < N) v = *(const float4*)(x + (size_t)row * 128 + c4);
        ushort4 u;
        u.x = f2b(v.x); u.y = f2b(v.y); u.z = f2b(v.z); u.w = f2b(v.w);
        *(ushort4*)(&xs[r * 132 + c4]) = u;
    }
    __syncthreads();
    const int tx = t & 15;   // cols 4tx..4tx+3 (head tx>>1)
    const int ty = t >> 4;   // rows 4ty..4ty+3
    float acc[4][4] = {};
#pragma unroll 2
    for (int kc = 0; kc < 32; ++kc) {
        float a_[4][4];
#pragma unroll
        for (int i = 0; i < 4; ++i) {
            ushort4 u = *(const ushort4*)(&xs[(4 * ty + i) * 132 + kc * 4]);
            a_[i][0] = b2f(u.x); a_[i][1] = b2f(u.y); a_[i][2] = b2f(u.z); a_[i][3] = b2f(u.w);
        }
        float4 w[4];
#pragma unroll
        for (int kk = 0; kk < 4; ++kk) w[kk] = *(const float4*)(W + (size_t)(kc * 4 + kk) * 64 + tx * 4);
#pragma unroll
        for (int i = 0; i < 4; ++i) {
#pragma unroll
            for (int j = 0; j < 4; ++j) {
                acc[i][j] += a_[i][0] * ((const float*)&w[0])[j]
                           + a_[i][1] * ((const float*)&w[1])[j]
                           + a_[i][2] * ((const float*)&w[2])[j]
                           + a_[i][3] * ((const float*)&w[3])[j];
            }
        }
    }
    const int h = tx >> 1;
    float4 av = *(const float4*)(asrc + tx * 4);
    float4 dv = *(const float4*)(adst + tx * 4);
    __syncthreads();                         // xs bf16 reads done; reuse as 96-B row staging
    unsigned char* qs = (unsigned char*)xs;  // 64 rows x 96 B = 6144 B
#pragma unroll
    for (int i = 0; i < 4; ++i) {
        int row = rowBase + 4 * ty + i;
        float ps = acc[i][0] * av.x + acc[i][1] * av.y + acc[i][2] * av.z + acc[i][3] * av.w;
        float pd = acc[i][0] * dv.x + acc[i][1] * dv.y + acc[i][2] * dv.z + acc[i][3] * dv.w;
        ps += __shfl_xor(ps, 1);
        pd += __shfl_xor(pd, 1);
        *(int*)(qs + (4 * ty + i) * 96 + h * 12 + (tx & 1) * 4) =
            f2q4(acc[i][0], acc[i][1], acc[i][2], acc[i][3]);
        if ((tx & 1) == 0) {
            *(unsigned short*)(qs + (4 * ty + i) * 96 + h * 12 + 8) = f2b(ps);
            if (row < N) ald[(size_t)row * 8 + h] = pd;
        }
    }
    __syncthreads();
    // coalesced copy-out: 64 rows x 96 B = 1536 uints
    for (int g = t; g < 1536; g += 256) {
        int row = g / 24;
        if (rowBase + row < N)
            *(unsigned int*)(h1q + (size_t)rowBase * 96 + (size_t)g * 4) = ((unsigned int*)qs)[g];
    }
}

// ---------------- FUSED layer-1 aggregation + GEMM2 + alpha2 ----------------
// Phase A: 1 lane per (node, head): 3 dword loads from ONE 96-B row per edge;
// 8-wide branch-free batching; zero-shuffle. Phase B: gemm2 on a 32-row bf16
// tile. The aggs pay the intrinsic cold-gather fill bill (~140 MB of L2
// fills after the build's scatter storm); R11-R13 showed barriers, row
// layout, and cache warming are all null or zero-sum against it.
__global__ __launch_bounds__(256) void k_ag(const int* __restrict__ cnt, const int* __restrict__ bucket,
                                            const unsigned char* __restrict__ h1q,
                                            const float* __restrict__ aldin,
                                            const float* __restrict__ b1,
                                            const float* __restrict__ W,
                                            const float* __restrict__ asrc,
                                            const float* __restrict__ adst,
                                            unsigned char* __restrict__ h2q,
                                            float* __restrict__ ald, int N) {
    __shared__ unsigned short xs[32 * 68];   // bf16 agg1 output; reused as fp8 staging
    __shared__ unsigned short wt[80 * 68];   // bf16 W2^T
    const int t = threadIdx.x;
    const int rowBase = blockIdx.x * 32;
    // stage W2^T in bf16 (needed only in phase B; issued first to overlap phase A)
#pragma unroll
    for (int i = 0; i < 20; ++i) {
        int g = i * 256 + t;
        int k = g / 80, c = g % 80;
        wt[c * 68 + k] = f2b(W[g]);
    }
    // ---- phase A: 1 lane per (node, head); 8 lanes/node ----
    {
        const int nl = t >> 3;               // local node 0..31
        const int h = t & 7;
        const int n = rowBase + nl;
        if (n < N) {
            const float aldh = aldin[(size_t)n * 8 + h];
            float acc[8] = {};
            float den = 0.f;
            auto body = [&](int m0, int m1, int m2, float val) {
                float a_s = b2f((unsigned short)(m2 & 0xFFFF));
                float wl = __expf(lrelu(a_s + aldh)) * val;
                den += wl;
                f32x2 v;
                v = __builtin_amdgcn_cvt_pk_f32_fp8(m0, false); acc[0] += wl * v.x; acc[1] += wl * v.y;
                v = __builtin_amdgcn_cvt_pk_f32_fp8(m0, true);  acc[2] += wl * v.x; acc[3] += wl * v.y;
                v = __builtin_amdgcn_cvt_pk_f32_fp8(m1, false); acc[4] += wl * v.x; acc[5] += wl * v.y;
                v = __builtin_amdgcn_cvt_pk_f32_fp8(m1, true);  acc[6] += wl * v.x; acc[7] += wl * v.y;
            };
            {   // self loop
                const unsigned char* r = h1q + (size_t)n * 96 + h * 12;
                body(*(const int*)r, *(const int*)(r + 4), *(const int*)(r + 8), 1.f);
            }
            const int k = min(cnt[n], CAP);
            const int* bp = bucket + (size_t)n * CAP;
            if (k > 0) {
                const int kg4 = ((k - 1) >> 2) << 2;       // last valid 4-group start
                int4 lo = *(const int4*)(bp);
                int4 hi = *(const int4*)(bp + min(4, kg4));
                for (int i0 = 0; i0 < k; i0 += 8) {
                    int4 cA = lo, cB = hi;
                    lo = *(const int4*)(bp + min(i0 + 8, kg4));    // always-safe prefetch
                    hi = *(const int4*)(bp + min(i0 + 12, kg4));
                    const int rem = k - i0;
                    int s[8];
                    s[0] = cA.x;
                    s[1] = (rem > 1) ? cA.y : cA.x;
                    s[2] = (rem > 2) ? cA.z : cA.x;
                    s[3] = (rem > 3) ? cA.w : cA.x;
                    s[4] = (rem > 4) ? cB.x : cA.x;
                    s[5] = (rem > 5) ? cB.y : cA.x;
                    s[6] = (rem > 6) ? cB.z : cA.x;
                    s[7] = (rem > 7) ? cB.w : cA.x;
                    int m0[8], m1[8], m2[8];
#pragma unroll
                    for (int j = 0; j < 8; ++j) {
                        const unsigned char* p = h1q + (size_t)s[j] * 96 + h * 12;
                        m0[j] = *(const int*)p;
                        m1[j] = *(const int*)(p + 4);
                        m2[j] = *(const int*)(p + 8);
                    }
#pragma unroll
                    for (int j = 0; j < 8; ++j) body(m0[j], m1[j], m2[j], (rem > j) ? 1.f : 0.f);
                }
            }
            float inv = 1.f / den;
            float o[8];
#pragma unroll
            for (int j = 0; j < 8; ++j) {
                float v = acc[j] * inv + b1[h * 8 + j];
                o[j] = v > 0.f ? v : __expf(v) - 1.f;
            }
            unsigned short* dst = &xs[nl * 68 + h * 8];
            ushort4 u0, u1;
            u0.x = f2b(o[0]); u0.y = f2b(o[1]); u0.z = f2b(o[2]); u0.w = f2b(o[3]);
            u1.x = f2b(o[4]); u1.y = f2b(o[5]); u1.z = f2b(o[6]); u1.w = f2b(o[7]);
            *(ushort4*)(dst) = u0;
            *(ushort4*)(dst + 4) = u1;
        }
    }
    __syncthreads();
    // ---- phase B: gemm2 + alpha2 on 32-row tile ----
    const int tx = t & 15;   // cols 5tx..5tx+4 (head tx>>1)
    const int ty = t >> 4;   // rows 2ty, 2ty+1
    float acc[2][5] = {};
#pragma unroll 4
    for (int kc = 0; kc < 16; ++kc) {
        float4 a[2];
#pragma unroll
        for (int i = 0; i < 2; ++i) {
            ushort4 u = *(const ushort4*)(&xs[(2 * ty + i) * 68 + kc * 4]);
            a[i] = make_float4(b2f(u.x), b2f(u.y), b2f(u.z), b2f(u.w));
        }
        float4 w[5];
#pragma unroll
        for (int j = 0; j < 5; ++j) {
            ushort4 u = *(const ushort4*)(&wt[(5 * tx + j) * 68 + kc * 4]);
            w[j] = make_float4(b2f(u.x), b2f(u.y), b2f(u.z), b2f(u.w));
        }
#pragma unroll
        for (int i = 0; i < 2; ++i) {
#pragma unroll
            for (int j = 0; j < 5; ++j) {
                acc[i][j] += a[i].x * w[j].x + a[i].y * w[j].y + a[i].z * w[j].z + a[i].w * w[j].w;
            }
        }
    }
    const int h = tx >> 1;
    float a2[5], d2[5];
#pragma unroll
    for (int j = 0; j < 5; ++j) { a2[j] = asrc[tx * 5 + j]; d2[j] = adst[tx * 5 + j]; }
    __syncthreads();                         // xs reads done; reuse as staging
    unsigned char* qs = (unsigned char*)xs;  // 32 rows x 96 B = 3072 B
#pragma unroll
    for (int i = 0; i < 2; ++i) {
        int row = rowBase + 2 * ty + i;
        float ps = 0.f, pd = 0.f;
#pragma unroll
        for (int j = 0; j < 5; ++j) { ps += acc[i][j] * a2[j]; pd += acc[i][j] * d2[j]; }
        ps += __shfl_xor(ps, 1);
        pd += __shfl_xor(pd, 1);
        int p0 = __builtin_amdgcn_cvt_pk_fp8_f32(acc[i][0], acc[i][1], 0, false);
        int p1 = __builtin_amdgcn_cvt_pk_fp8_f32(acc[i][2], acc[i][3], 0, false);
        int p2 = __builtin_amdgcn_cvt_pk_fp8_f32(acc[i][4], acc[i][4], 0, false);
        unsigned char* q = qs + (2 * ty + i) * 96 + h * 12 + (tx & 1) * 5;
        q[0] = (unsigned char)(p0 & 0xFF);
        q[1] = (unsigned char)((p0 >> 8) & 0xFF);
        q[2] = (unsigned char)(p1 & 0xFF);
        q[3] = (unsigned char)((p1 >> 8) & 0xFF);
        q[4] = (unsigned char)(p2 & 0xFF);
        if ((tx & 1) == 0) {
            *(unsigned short*)(qs + (size_t)(2 * ty + i) * 96 + h * 12 + 10) = f2b(ps);
            if (row < N) ald[(size_t)row * 8 + h] = pd;
        }
    }
    __syncthreads();
    // coalesced copy-out: 32 rows x 96 B = 768 uints
    for (int g = t; g < 768; g += 256) {
        int row = g / 24;
        if (rowBase + row < N)
            *(unsigned int*)(h2q + (size_t)rowBase * 96 + (size_t)g * 4) = ((unsigned int*)qs)[g];
    }
}

// ---------------- layer-2 aggregation (unchanged -- the proven-fast kernel) ----------------
__global__ __launch_bounds__(256) void k_agg2(const int* __restrict__ cnt, const int* __restrict__ bucket,
                                              const unsigned char* __restrict__ h2q,
                                              const float* __restrict__ ald,
                                              const float* __restrict__ b2,
                                              float* __restrict__ out, int N) {
    const int t = threadIdx.x;
    const int n = blockIdx.x * 32 + (t >> 3);
    const int h = t & 7;
    if (n >= N) return;
    float acc[10] = {};
    float den = 0.f;
    const float aldh = ald[(size_t)n * 8 + h];
    auto body = [&](int m0, int m1, int m2, float val) {
        float a_s = b2f((unsigned short)(((unsigned)m2) >> 16));
        float wl = __expf(lrelu(a_s + aldh)) * val;
        den += wl;
        f32x2 v;
        v = __builtin_amdgcn_cvt_pk_f32_fp8(m0, false); acc[0] += wl * v.x; acc[1] += wl * v.y;
        v = __builtin_amdgcn_cvt_pk_f32_fp8(m0, true);  acc[2] += wl * v.x; acc[3] += wl * v.y;
        v = __builtin_amdgcn_cvt_pk_f32_fp8(m1, false); acc[4] += wl * v.x; acc[5] += wl * v.y;
        v = __builtin_amdgcn_cvt_pk_f32_fp8(m1, true);  acc[6] += wl * v.x; acc[7] += wl * v.y;
        v = __builtin_amdgcn_cvt_pk_f32_fp8(m2, false); acc[8] += wl * v.x; acc[9] += wl * v.y;
    };
    {   // self loop
        const unsigned char* r = h2q + (size_t)n * 96 + h * 12;
        body(*(const int*)r, *(const int*)(r + 4), *(const int*)(r + 8), 1.f);
    }
    const int k = min(cnt[n], CAP);
    const int* bp = bucket + (size_t)n * CAP;
    if (k > 0) {
        const int kg4 = ((k - 1) >> 2) << 2;       // last valid 4-group start
        int4 lo = *(const int4*)(bp);
        int4 hi = *(const int4*)(bp + min(4, kg4));
        for (int i0 = 0; i0 < k; i0 += 8) {
            int4 cA = lo, cB = hi;
            lo = *(const int4*)(bp + min(i0 + 8, kg4));    // always-safe prefetch
            hi = *(const int4*)(bp + min(i0 + 12, kg4));
            const int rem = k - i0;
            int s[8];
            s[0] = cA.x;
            s[1] = (rem > 1) ? cA.y : cA.x;
            s[2] = (rem > 2) ? cA.z : cA.x;
            s[3] = (rem > 3) ? cA.w : cA.x;
            s[4] = (rem > 4) ? cB.x : cA.x;
            s[5] = (rem > 5) ? cB.y : cA.x;
            s[6] = (rem > 6) ? cB.z : cA.x;
            s[7] = (rem > 7) ? cB.w : cA.x;
            int m0[8], m1[8], m2[8];
#pragma unroll
            for (int j = 0; j < 8; ++j) {
                const unsigned char* p = h2q + (size_t)s[j] * 96 + h * 12;
                m0[j] = *(const int*)p;
                m1[j] = *(const int*)(p + 4);
                m2[j] = *(const int*)(p + 8);
            }
#pragma unroll
            for (int j = 0; j < 8; ++j) body(m0[j], m1[j], m2[j], (rem > j) ? 1.f : 0.f);
        }
    }
    float inv = 1.f / den;
#pragma unroll
    for (int j = 0; j < 10; ++j) acc[j] *= inv;
    // mean over 8 heads: butterfly within the 8-lane group (offsets 1,2,4)
#pragma unroll
    for (int off = 1; off < 8; off <<= 1) {
#pragma unroll
        for (int j = 0; j < 10; ++j) acc[j] += __shfl_xor(acc[j], off);
    }
    if (h == 0) {
        float m[10];
#pragma unroll
        for (int j = 0; j < 10; ++j) m[j] = acc[j] * 0.125f + b2[j];
        float mx = -1e30f;
#pragma unroll
        for (int j = 0; j < 10; ++j) mx = fmaxf(mx, m[j]);
        float ssum = 0.f;
#pragma unroll
        for (int j = 0; j < 10; ++j) ssum += __expf(m[j] - mx);
        float lg = __logf(ssum);
#pragma unroll
        for (int j = 0; j < 10; ++j) out[(size_t)n * 10 + j] = m[j] - mx - lg;
    }
}

extern "C" void kernel_launch(void* const* d_in, const int* in_sizes, int n_in,
                              void* d_out, int out_size, void* d_ws, size_t ws_size,
                              hipStream_t stream) {
    const float* x     = (const float*)d_in[0];
    const int*   ei    = (const int*)d_in[1];
    const float* W1    = (const float*)d_in[2];
    const float* asrc1 = (const float*)d_in[3];
    const float* adst1 = (const float*)d_in[4];
    const float* b1    = (const float*)d_in[5];
    const float* W2    = (const float*)d_in[6];
    const float* asrc2 = (const float*)d_in[7];
    const float* adst2 = (const float*)d_in[8];
    const float* b2    = (const float*)d_in[9];
    float* out = (float*)d_out;

    int N = in_sizes[0] / 128;
    int E = in_sizes[1] / 2;

    char* base = (char*)d_ws;
    size_t off = 0;
    auto alloc = [&](size_t bytes) {
        char* p = base + off;
        off = (off + bytes + 255) & ~(size_t)255;
        return p;
    };
    int*            cnt    = (int*)alloc((size_t)N * 4);
    int*            bucket = (int*)alloc((size_t)N * CAP * 4);
    unsigned char*  h1q    = (unsigned char*)alloc((size_t)N * 96);  // layer-1: 8 heads x [8 fp8 | bf16 als | pad]
    unsigned char*  h2q    = (unsigned char*)alloc((size_t)N * 96);  // layer-2: 8 heads x [10 fp8 | bf16 als]
    float*          ald    = (float*)alloc((size_t)N * 8 * 4);       // layer1 then layer2
    (void)ws_size; (void)n_in; (void)out_size;

    (void)hipMemsetAsync(cnt, 0, (size_t)N * 4, stream);
    int chunks = (E + CHUNK_EDGES - 1) / CHUNK_EDGES;
    int buildBlocks = chunks * SLICES;
    int gemmBlocks = (N + 63) / 64;
    k_bg<<<buildBlocks + gemmBlocks, 256, 0, stream>>>(ei, E, N, cnt, bucket,
                                                       x, W1, asrc1, adst1, h1q, ald, buildBlocks);
    k_ag<<<(N + 31) / 32, 256, 0, stream>>>(cnt, bucket, h1q, ald, b1,
                                            W2, asrc2, adst2, h2q, ald, N);
    k_agg2<<<(N + 31) / 32, 256, 0, stream>>>(cnt, bucket, h2q, ald, b2, out, N);
}